// Round 1
// baseline (187.007 us; speedup 1.0000x reference)
//
#include <hip/hip_runtime.h>
#include <hip/hip_bf16.h>
#include <math.h>

// ---------------------------------------------------------------------------
// ColorizationNet inference, restructured:
//   base[304] = w1[:, :32768] @ x_conv + b1      (once; w1 read exactly once)
//   per chunk c=(i,j):  h1 = relu(base + W1pc @ [4i,4j,chunk16])
//                       h2 = relu(W2 @ h1 + b2)
//                       out = sigmoid(W3 @ h2 + b3)
// ---------------------------------------------------------------------------

#define G_   64
#define CONV_FLAT 32768
#define H1_  304
#define H2_  176
#define OUT_ 48

// ws layout (float offsets)
#define WS_C1    0          // 8*128*128   = 131072
#define WS_C2    131072     // 16*64*64    = 65536
#define WS_XC    196608     // 32*32*32    = 32768
#define WS_BASE  229376     // 304
#define WS_W1PCT 229680     // 18*304      = 5472
#define WS_W2T   235152     // 304*176     = 53504
#define WS_W3T   288656     // 176*48      = 8448
// total = 297104 floats ~= 1.19 MB

__global__ void conv1_k(const float* __restrict__ x, const float* __restrict__ w,
                        const float* __restrict__ b, float* __restrict__ out) {
    int idx = blockIdx.x * blockDim.x + threadIdx.x;       // 8*128*128
    if (idx >= 8 * 128 * 128) return;
    int o = idx >> 14;
    int p = idx & 16383;
    int py = p >> 7, px = p & 127;
    float wv[9];
#pragma unroll
    for (int k = 0; k < 9; k++) wv[k] = w[o * 9 + k];
    float bias = b[o];
    float mx = -1e30f;
#pragma unroll
    for (int dy = 0; dy < 2; dy++) {
#pragma unroll
        for (int dx = 0; dx < 2; dx++) {
            int y = 2 * py + dy, xx = 2 * px + dx;
            float acc = bias;
#pragma unroll
            for (int ky = 0; ky < 3; ky++) {
                int sy = y + ky - 1;
                if (sy < 0 || sy > 255) continue;
#pragma unroll
                for (int kx = 0; kx < 3; kx++) {
                    int sx = xx + kx - 1;
                    if (sx < 0 || sx > 255) continue;
                    acc += x[sy * 256 + sx] * wv[ky * 3 + kx];
                }
            }
            mx = fmaxf(mx, acc);
        }
    }
    out[idx] = fmaxf(mx, 0.f);
}

__global__ void conv2_k(const float* __restrict__ in, const float* __restrict__ w,
                        const float* __restrict__ b, float* __restrict__ out) {
    int idx = blockIdx.x * blockDim.x + threadIdx.x;       // 16*64*64
    if (idx >= 16 * 64 * 64) return;
    int o = idx >> 12;
    int p = idx & 4095;
    int py = p >> 6, px = p & 63;
    float mx = -1e30f;
#pragma unroll
    for (int dy = 0; dy < 2; dy++) {
#pragma unroll
        for (int dx = 0; dx < 2; dx++) {
            int y = 2 * py + dy, xx = 2 * px + dx;
            float acc = b[o];
            for (int c = 0; c < 8; c++) {
                const float* inc = in + c * 16384;
                const float* wc  = w + (o * 8 + c) * 9;
#pragma unroll
                for (int ky = 0; ky < 3; ky++) {
                    int sy = y + ky - 1;
                    if (sy < 0 || sy > 127) continue;
#pragma unroll
                    for (int kx = 0; kx < 3; kx++) {
                        int sx = xx + kx - 1;
                        if (sx < 0 || sx > 127) continue;
                        acc += inc[sy * 128 + sx] * wc[ky * 3 + kx];
                    }
                }
            }
            mx = fmaxf(mx, acc);
        }
    }
    out[idx] = fmaxf(mx, 0.f);
}

__global__ void conv3_k(const float* __restrict__ in, const float* __restrict__ w,
                        const float* __restrict__ b, float* __restrict__ out) {
    int idx = blockIdx.x * blockDim.x + threadIdx.x;       // 32*32*32
    if (idx >= 32 * 32 * 32) return;
    int o = idx >> 10;
    int p = idx & 1023;
    int py = p >> 5, px = p & 31;
    float mx = -1e30f;
#pragma unroll
    for (int dy = 0; dy < 2; dy++) {
#pragma unroll
        for (int dx = 0; dx < 2; dx++) {
            int y = 2 * py + dy, xx = 2 * px + dx;
            float acc = b[o];
            for (int c = 0; c < 16; c++) {
                const float* inc = in + c * 4096;
                const float* wc  = w + (o * 16 + c) * 9;
#pragma unroll
                for (int ky = 0; ky < 3; ky++) {
                    int sy = y + ky - 1;
                    if (sy < 0 || sy > 63) continue;
#pragma unroll
                    for (int kx = 0; kx < 3; kx++) {
                        int sx = xx + kx - 1;
                        if (sx < 0 || sx > 63) continue;
                        acc += inc[sy * 64 + sx] * wc[ky * 3 + kx];
                    }
                }
            }
            mx = fmaxf(mx, acc);
        }
    }
    // natural layout == x_conv flatten order [c][y][x]
    out[idx] = fmaxf(mx, 0.f);
}

// base[row] = b1[row] + sum_k w1[row, k] * xconv[k], k < 32768  (w1 row stride 32786)
__global__ void base_k(const float* __restrict__ w1, const float* __restrict__ xconv,
                       const float* __restrict__ b1, float* __restrict__ base) {
    int row = blockIdx.x;
    const float* wr = w1 + (size_t)row * 32786;
    float acc = 0.f;
    for (int k = threadIdx.x; k < CONV_FLAT; k += 256)
        acc += wr[k] * xconv[k];
#pragma unroll
    for (int off = 32; off > 0; off >>= 1)
        acc += __shfl_down(acc, off, 64);
    __shared__ float red[4];
    int lane = threadIdx.x & 63, wid = threadIdx.x >> 6;
    if (lane == 0) red[wid] = acc;
    __syncthreads();
    if (threadIdx.x == 0)
        base[row] = red[0] + red[1] + red[2] + red[3] + b1[row];
}

// transpose small weights for coalesced reads in chunk kernel
__global__ void prep_k(const float* __restrict__ w1, const float* __restrict__ w2,
                       const float* __restrict__ w3, float* __restrict__ w1pcT,
                       float* __restrict__ w2T, float* __restrict__ w3T) {
    int idx = blockIdx.x * blockDim.x + threadIdx.x;
    if (idx < 304 * 176) {                       // w2T[k*176+t] = w2[t*304+k]
        int k = idx / 176, t = idx - k * 176;
        w2T[idx] = w2[t * 304 + k];
    }
    if (idx < 176 * 48) {                        // w3T[k*48+t] = w3[t*176+k]
        int k = idx / 48, t = idx - k * 48;
        w3T[idx] = w3[t * 176 + k];
    }
    if (idx < 18 * 304) {                        // w1pcT[k*304+t] = w1[t, 32768+k]
        int k = idx / 304, t = idx - k * 304;
        w1pcT[idx] = w1[(size_t)t * 32786 + 32768 + k];
    }
}

// fused per-chunk MLP, 8 chunks per block
__global__ void chunk_k(const float* __restrict__ x, const float* __restrict__ base,
                        const float* __restrict__ w1pcT, const float* __restrict__ w2T,
                        const float* __restrict__ b2, const float* __restrict__ w3T,
                        const float* __restrict__ b3, float* __restrict__ out) {
    __shared__ float pc[8][18];
    __shared__ float h1[8][H1_];
    __shared__ float h2[8][H2_];
    int tid = threadIdx.x;
    int c0 = blockIdx.x * 8;

    if (tid < 8 * 18) {
        int u = tid / 18, k = tid - u * 18;
        int c = c0 + u;
        int i = c >> 6, j = c & 63;
        float v;
        if (k == 0)      v = (float)(i * 4);
        else if (k == 1) v = (float)(j * 4);
        else {
            int kk = k - 2;
            int r = kk >> 2, cc = kk & 3;
            v = x[(i * 4 + r) * 256 + j * 4 + cc];
        }
        pc[u][k] = v;
    }
    __syncthreads();

    // h1: 304 outputs x 8 chunks
    for (int t = tid; t < H1_; t += 256) {
        float bb = base[t];
        float acc[8];
#pragma unroll
        for (int u = 0; u < 8; u++) acc[u] = bb;
        for (int k = 0; k < 18; k++) {
            float w = w1pcT[k * H1_ + t];
#pragma unroll
            for (int u = 0; u < 8; u++) acc[u] += w * pc[u][k];
        }
#pragma unroll
        for (int u = 0; u < 8; u++) h1[u][t] = fmaxf(acc[u], 0.f);
    }
    __syncthreads();

    // h2: 176 outputs x 8 chunks
    if (tid < H2_) {
        float bb = b2[tid];
        float acc[8];
#pragma unroll
        for (int u = 0; u < 8; u++) acc[u] = bb;
        for (int k = 0; k < H1_; k++) {
            float w = w2T[k * H2_ + tid];
#pragma unroll
            for (int u = 0; u < 8; u++) acc[u] += w * h1[u][k];
        }
#pragma unroll
        for (int u = 0; u < 8; u++) h2[u][tid] = fmaxf(acc[u], 0.f);
    }
    __syncthreads();

    // out: 48 outputs x 8 chunks = 384
    for (int idx = tid; idx < 8 * OUT_; idx += 256) {
        int u = idx / OUT_, t = idx - u * OUT_;
        float acc = b3[t];
        for (int k = 0; k < H2_; k++)
            acc += w3T[k * OUT_ + t] * h2[u][k];
        out[(size_t)(c0 + u) * OUT_ + t] = 1.f / (1.f + expf(-acc));
    }
}

extern "C" void kernel_launch(void* const* d_in, const int* in_sizes, int n_in,
                              void* d_out, int out_size, void* d_ws, size_t ws_size,
                              hipStream_t stream) {
    const float* x    = (const float*)d_in[0];
    const float* c1_w = (const float*)d_in[1];
    const float* c1_b = (const float*)d_in[2];
    const float* c2_w = (const float*)d_in[3];
    const float* c2_b = (const float*)d_in[4];
    const float* c3_w = (const float*)d_in[5];
    const float* c3_b = (const float*)d_in[6];
    const float* w1   = (const float*)d_in[7];
    const float* b1   = (const float*)d_in[8];
    const float* w2   = (const float*)d_in[9];
    const float* b2   = (const float*)d_in[10];
    const float* w3   = (const float*)d_in[11];
    const float* b3   = (const float*)d_in[12];
    float* out = (float*)d_out;
    float* ws  = (float*)d_ws;

    float* c1o    = ws + WS_C1;
    float* c2o    = ws + WS_C2;
    float* xconv  = ws + WS_XC;
    float* base   = ws + WS_BASE;
    float* w1pcT  = ws + WS_W1PCT;
    float* w2T    = ws + WS_W2T;
    float* w3T    = ws + WS_W3T;

    prep_k<<<(304 * 176 + 255) / 256, 256, 0, stream>>>(w1, w2, w3, w1pcT, w2T, w3T);
    conv1_k<<<512, 256, 0, stream>>>(x, c1_w, c1_b, c1o);
    conv2_k<<<256, 256, 0, stream>>>(c1o, c2_w, c2_b, c2o);
    conv3_k<<<128, 256, 0, stream>>>(c2o, c3_w, c3_b, xconv);
    base_k<<<H1_, 256, 0, stream>>>(w1, xconv, b1, base);
    chunk_k<<<512, 256, 0, stream>>>(x, base, w1pcT, w2T, b2, w3T, b3, out);
}

// Round 2
// 125.645 us; speedup vs baseline: 1.4884x; 1.4884x over previous
//
#include <hip/hip_runtime.h>
#include <hip/hip_bf16.h>
#include <math.h>

// ---------------------------------------------------------------------------
// ColorizationNet inference, restructured:
//   base[304] = w1[:, :32768] @ x_conv + b1      (split-K, atomic accumulate)
//   per chunk c=(i,j):  h1 = relu(base + W1pc @ [4i,4j,chunk16])
//                       h2 = relu(W2 @ h1 + b2)
//                       out = sigmoid(W3 @ h2 + b3)
// Convs computed at pre-pool resolution (4x threads), 2x2 pool via shfl_xor.
// ---------------------------------------------------------------------------

#define CONV_FLAT 32768
#define H1_  304
#define H2_  176
#define OUT_ 48

// ws layout (float offsets)
#define WS_C1    0          // 8*128*128   = 131072
#define WS_C2    131072     // 16*64*64    = 65536
#define WS_XC    196608     // 32*32*32    = 32768
#define WS_BASE  229376     // 304
#define WS_W1PCT 229680     // 18*304      = 5472
#define WS_W2T   235152     // 304*176    = 53504
#define WS_W3T   288656     // 176*48     = 8448

__global__ void conv1_k(const float* __restrict__ x, const float* __restrict__ w,
                        const float* __restrict__ b, float* __restrict__ out) {
    int idx = blockIdx.x * blockDim.x + threadIdx.x;   // 8*128*128*4
    int sub = idx & 3;                  // y0*2 + x0 within pool quad
    int p   = idx >> 2;                 // pooled index: o*16384 + py*128 + px
    int o  = p >> 14;
    int py = (p >> 7) & 127, px = p & 127;
    int y = py * 2 + (sub >> 1), xx = px * 2 + (sub & 1);
    float acc = b[o];
    const float* wo = w + o * 9;
#pragma unroll
    for (int ky = 0; ky < 3; ky++) {
        int sy = y + ky - 1;
        if ((unsigned)sy > 255u) continue;
        const float* row = x + sy * 256;
#pragma unroll
        for (int kx = 0; kx < 3; kx++) {
            int sx = xx + kx - 1;
            if ((unsigned)sx > 255u) continue;
            acc += row[sx] * wo[ky * 3 + kx];
        }
    }
    acc = fmaxf(acc, __shfl_xor(acc, 1, 64));
    acc = fmaxf(acc, __shfl_xor(acc, 2, 64));
    if (sub == 0) out[p] = fmaxf(acc, 0.f);
}

__global__ void conv2_k(const float* __restrict__ in, const float* __restrict__ w,
                        const float* __restrict__ b, float* __restrict__ out) {
    int idx = blockIdx.x * blockDim.x + threadIdx.x;   // 16*64*64*4
    int sub = idx & 3;
    int p   = idx >> 2;                 // o*4096 + py*64 + px
    int o  = p >> 12;
    int py = (p >> 6) & 63, px = p & 63;
    int y = py * 2 + (sub >> 1), xx = px * 2 + (sub & 1);
    float acc = b[o];
    const float* wo = w + o * 72;
    for (int c = 0; c < 8; c++) {
        const float* inc = in + c * 16384;
        const float* wc  = wo + c * 9;
#pragma unroll
        for (int ky = 0; ky < 3; ky++) {
            int sy = y + ky - 1;
            if ((unsigned)sy > 127u) continue;
            const float* row = inc + sy * 128;
#pragma unroll
            for (int kx = 0; kx < 3; kx++) {
                int sx = xx + kx - 1;
                if ((unsigned)sx > 127u) continue;
                acc += row[sx] * wc[ky * 3 + kx];
            }
        }
    }
    acc = fmaxf(acc, __shfl_xor(acc, 1, 64));
    acc = fmaxf(acc, __shfl_xor(acc, 2, 64));
    if (sub == 0) out[p] = fmaxf(acc, 0.f);
}

__global__ void conv3_k(const float* __restrict__ in, const float* __restrict__ w,
                        const float* __restrict__ b, float* __restrict__ out) {
    int idx = blockIdx.x * blockDim.x + threadIdx.x;   // 32*32*32*4
    int sub = idx & 3;
    int p   = idx >> 2;                 // o*1024 + py*32 + px
    int o  = p >> 10;
    int py = (p >> 5) & 31, px = p & 31;
    int y = py * 2 + (sub >> 1), xx = px * 2 + (sub & 1);
    float acc = b[o];
    const float* wo = w + o * 144;
    for (int c = 0; c < 16; c++) {
        const float* inc = in + c * 4096;
        const float* wc  = wo + c * 9;
#pragma unroll
        for (int ky = 0; ky < 3; ky++) {
            int sy = y + ky - 1;
            if ((unsigned)sy > 63u) continue;
            const float* row = inc + sy * 64;
#pragma unroll
            for (int kx = 0; kx < 3; kx++) {
                int sx = xx + kx - 1;
                if ((unsigned)sx > 63u) continue;
                acc += row[sx] * wc[ky * 3 + kx];
            }
        }
    }
    acc = fmaxf(acc, __shfl_xor(acc, 1, 64));
    acc = fmaxf(acc, __shfl_xor(acc, 2, 64));
    if (sub == 0) out[p] = fmaxf(acc, 0.f);   // layout == x_conv flatten [c][y][x]
}

// split-K: base[row] += partial dot(w1[row, seg], xconv[seg]); base pre-init to b1
#define NSEG 16
#define SEGLEN (CONV_FLAT / NSEG)   // 2048 floats
__global__ void base_acc_k(const float* __restrict__ w1, const float* __restrict__ xconv,
                           float* __restrict__ base) {
    int row = blockIdx.x >> 4;
    int seg = blockIdx.x & 15;
    const float2* wr = (const float2*)(w1 + (size_t)row * 32786) + seg * (SEGLEN / 2);
    const float2* xc = (const float2*)(xconv) + seg * (SEGLEN / 2);
    float acc = 0.f;
#pragma unroll
    for (int i = 0; i < 4; i++) {
        float2 a = wr[threadIdx.x + i * 256];
        float2 v = xc[threadIdx.x + i * 256];
        acc += a.x * v.x + a.y * v.y;
    }
#pragma unroll
    for (int off = 32; off > 0; off >>= 1)
        acc += __shfl_down(acc, off, 64);
    __shared__ float red[4];
    int lane = threadIdx.x & 63, wid = threadIdx.x >> 6;
    if (lane == 0) red[wid] = acc;
    __syncthreads();
    if (threadIdx.x == 0)
        atomicAdd(&base[row], red[0] + red[1] + red[2] + red[3]);
}

// transpose small weights + init base = b1 (re-done every call: graph-replay safe)
__global__ void prep_k(const float* __restrict__ w1, const float* __restrict__ w2,
                       const float* __restrict__ w3, const float* __restrict__ b1,
                       float* __restrict__ w1pcT, float* __restrict__ w2T,
                       float* __restrict__ w3T, float* __restrict__ base) {
    int idx = blockIdx.x * blockDim.x + threadIdx.x;
    if (idx < 304 * 176) {                       // w2T[k*176+t] = w2[t*304+k]
        int k = idx / 176, t = idx - k * 176;
        w2T[idx] = w2[t * 304 + k];
    }
    if (idx < 176 * 48) {                        // w3T[k*48+t] = w3[t*176+k]
        int k = idx / 48, t = idx - k * 48;
        w3T[idx] = w3[t * 176 + k];
    }
    if (idx < 18 * 304) {                        // w1pcT[k*304+t] = w1[t, 32768+k]
        int k = idx / 304, t = idx - k * 304;
        w1pcT[idx] = w1[(size_t)t * 32786 + 32768 + k];
    }
    if (idx < H1_) base[idx] = b1[idx];
}

// fused per-chunk MLP, 8 chunks per block
__global__ void chunk_k(const float* __restrict__ x, const float* __restrict__ base,
                        const float* __restrict__ w1pcT, const float* __restrict__ w2T,
                        const float* __restrict__ b2, const float* __restrict__ w3T,
                        const float* __restrict__ b3, float* __restrict__ out) {
    __shared__ float pc[8][18];
    __shared__ float h1[8][H1_];
    __shared__ float h2[8][H2_];
    int tid = threadIdx.x;
    int c0 = blockIdx.x * 8;

    if (tid < 8 * 18) {
        int u = tid / 18, k = tid - u * 18;
        int c = c0 + u;
        int i = c >> 6, j = c & 63;
        float v;
        if (k == 0)      v = (float)(i * 4);
        else if (k == 1) v = (float)(j * 4);
        else {
            int kk = k - 2;
            int r = kk >> 2, cc = kk & 3;
            v = x[(i * 4 + r) * 256 + j * 4 + cc];
        }
        pc[u][k] = v;
    }
    __syncthreads();

    // h1: 304 outputs x 8 chunks
    for (int t = tid; t < H1_; t += 256) {
        float bb = base[t];
        float acc[8];
#pragma unroll
        for (int u = 0; u < 8; u++) acc[u] = bb;
#pragma unroll
        for (int k = 0; k < 18; k++) {
            float w = w1pcT[k * H1_ + t];
#pragma unroll
            for (int u = 0; u < 8; u++) acc[u] += w * pc[u][k];
        }
#pragma unroll
        for (int u = 0; u < 8; u++) h1[u][t] = fmaxf(acc[u], 0.f);
    }
    __syncthreads();

    // h2: 176 outputs x 8 chunks
    if (tid < H2_) {
        float bb = b2[tid];
        float acc[8];
#pragma unroll
        for (int u = 0; u < 8; u++) acc[u] = bb;
#pragma unroll 4
        for (int k = 0; k < H1_; k++) {
            float w = w2T[k * H2_ + tid];
#pragma unroll
            for (int u = 0; u < 8; u++) acc[u] += w * h1[u][k];
        }
#pragma unroll
        for (int u = 0; u < 8; u++) h2[u][tid] = fmaxf(acc[u], 0.f);
    }
    __syncthreads();

    // out: 48 outputs x 8 chunks = 384
    for (int idx = tid; idx < 8 * OUT_; idx += 256) {
        int u = idx / OUT_, t = idx - u * OUT_;
        float acc = b3[t];
#pragma unroll 4
        for (int k = 0; k < H2_; k++)
            acc += w3T[k * OUT_ + t] * h2[u][k];
        out[(size_t)(c0 + u) * OUT_ + t] = 1.f / (1.f + expf(-acc));
    }
}

extern "C" void kernel_launch(void* const* d_in, const int* in_sizes, int n_in,
                              void* d_out, int out_size, void* d_ws, size_t ws_size,
                              hipStream_t stream) {
    const float* x    = (const float*)d_in[0];
    const float* c1_w = (const float*)d_in[1];
    const float* c1_b = (const float*)d_in[2];
    const float* c2_w = (const float*)d_in[3];
    const float* c2_b = (const float*)d_in[4];
    const float* c3_w = (const float*)d_in[5];
    const float* c3_b = (const float*)d_in[6];
    const float* w1   = (const float*)d_in[7];
    const float* b1   = (const float*)d_in[8];
    const float* w2   = (const float*)d_in[9];
    const float* b2   = (const float*)d_in[10];
    const float* w3   = (const float*)d_in[11];
    const float* b3   = (const float*)d_in[12];
    float* out = (float*)d_out;
    float* ws  = (float*)d_ws;

    float* c1o    = ws + WS_C1;
    float* c2o    = ws + WS_C2;
    float* xconv  = ws + WS_XC;
    float* base   = ws + WS_BASE;
    float* w1pcT  = ws + WS_W1PCT;
    float* w2T    = ws + WS_W2T;
    float* w3T    = ws + WS_W3T;

    prep_k<<<(304 * 176 + 255) / 256, 256, 0, stream>>>(w1, w2, w3, b1, w1pcT, w2T, w3T, base);
    conv1_k<<<2048, 256, 0, stream>>>(x, c1_w, c1_b, c1o);
    conv2_k<<<1024, 256, 0, stream>>>(c1o, c2_w, c2_b, c2o);
    conv3_k<<<512, 256, 0, stream>>>(c2o, c3_w, c3_b, xconv);
    base_acc_k<<<H1_ * NSEG, 256, 0, stream>>>(w1, xconv, base);
    chunk_k<<<512, 256, 0, stream>>>(x, base, w1pcT, w2T, b2, w3T, b3, out);
}

// Round 3
// 89.564 us; speedup vs baseline: 2.0880x; 1.4029x over previous
//
#include <hip/hip_runtime.h>
#include <hip/hip_bf16.h>
#include <math.h>

// ---------------------------------------------------------------------------
// ColorizationNet inference, restructured:
//   base[304] = w1[:, :32768] @ x_conv + b1      (split-K, atomic accumulate)
//   per chunk c=(i,j):  h1 = relu(base + W1pc @ [4i,4j,chunk16])
//                       h2 = relu(W2 @ h1 + b2)
//                       out = sigmoid(W3 @ h2 + b3)
// Convs computed at pre-pool resolution (4x threads), 2x2 pool via shfl_xor.
// chunk_k: 4 chunks/block, 1024 blocks; w2/w3 packed float4-along-k.
// ---------------------------------------------------------------------------

#define CONV_FLAT 32768
#define H1_  304
#define H2_  176
#define OUT_ 48

// ws layout (float offsets)
#define WS_C1    0          // 8*128*128   = 131072
#define WS_C2    131072     // 16*64*64    = 65536
#define WS_XC    196608     // 32*32*32    = 32768
#define WS_BASE  229376     // 304
#define WS_W1PCT 229680     // 18*304      = 5472
#define WS_W2Q   235152     // 76*176*4    = 53504   (w2 packed: [k/4][t][4])
#define WS_W3Q   288656     // 44*48*4     = 8448    (w3 packed: [k/4][t][4])

__global__ void conv1_k(const float* __restrict__ x, const float* __restrict__ w,
                        const float* __restrict__ b, float* __restrict__ out) {
    int idx = blockIdx.x * blockDim.x + threadIdx.x;   // 8*128*128*4
    int sub = idx & 3;                  // y0*2 + x0 within pool quad
    int p   = idx >> 2;                 // pooled index: o*16384 + py*128 + px
    int o  = p >> 14;
    int py = (p >> 7) & 127, px = p & 127;
    int y = py * 2 + (sub >> 1), xx = px * 2 + (sub & 1);
    float acc = b[o];
    const float* wo = w + o * 9;
#pragma unroll
    for (int ky = 0; ky < 3; ky++) {
        int sy = y + ky - 1;
        if ((unsigned)sy > 255u) continue;
        const float* row = x + sy * 256;
#pragma unroll
        for (int kx = 0; kx < 3; kx++) {
            int sx = xx + kx - 1;
            if ((unsigned)sx > 255u) continue;
            acc += row[sx] * wo[ky * 3 + kx];
        }
    }
    acc = fmaxf(acc, __shfl_xor(acc, 1, 64));
    acc = fmaxf(acc, __shfl_xor(acc, 2, 64));
    if (sub == 0) out[p] = fmaxf(acc, 0.f);
}

__global__ void conv2_k(const float* __restrict__ in, const float* __restrict__ w,
                        const float* __restrict__ b, float* __restrict__ out) {
    int idx = blockIdx.x * blockDim.x + threadIdx.x;   // 16*64*64*4
    int sub = idx & 3;
    int p   = idx >> 2;                 // o*4096 + py*64 + px
    int o  = p >> 12;
    int py = (p >> 6) & 63, px = p & 63;
    int y = py * 2 + (sub >> 1), xx = px * 2 + (sub & 1);
    float acc = b[o];
    const float* wo = w + o * 72;
    for (int c = 0; c < 8; c++) {
        const float* inc = in + c * 16384;
        const float* wc  = wo + c * 9;
#pragma unroll
        for (int ky = 0; ky < 3; ky++) {
            int sy = y + ky - 1;
            if ((unsigned)sy > 127u) continue;
            const float* row = inc + sy * 128;
#pragma unroll
            for (int kx = 0; kx < 3; kx++) {
                int sx = xx + kx - 1;
                if ((unsigned)sx > 127u) continue;
                acc += row[sx] * wc[ky * 3 + kx];
            }
        }
    }
    acc = fmaxf(acc, __shfl_xor(acc, 1, 64));
    acc = fmaxf(acc, __shfl_xor(acc, 2, 64));
    if (sub == 0) out[p] = fmaxf(acc, 0.f);
}

__global__ void conv3_k(const float* __restrict__ in, const float* __restrict__ w,
                        const float* __restrict__ b, float* __restrict__ out) {
    int idx = blockIdx.x * blockDim.x + threadIdx.x;   // 32*32*32*4
    int sub = idx & 3;
    int p   = idx >> 2;                 // o*1024 + py*32 + px
    int o  = p >> 10;
    int py = (p >> 5) & 31, px = p & 31;
    int y = py * 2 + (sub >> 1), xx = px * 2 + (sub & 1);
    float acc = b[o];
    const float* wo = w + o * 144;
    for (int c = 0; c < 16; c++) {
        const float* inc = in + c * 4096;
        const float* wc  = wo + c * 9;
#pragma unroll
        for (int ky = 0; ky < 3; ky++) {
            int sy = y + ky - 1;
            if ((unsigned)sy > 63u) continue;
            const float* row = inc + sy * 64;
#pragma unroll
            for (int kx = 0; kx < 3; kx++) {
                int sx = xx + kx - 1;
                if ((unsigned)sx > 63u) continue;
                acc += row[sx] * wc[ky * 3 + kx];
            }
        }
    }
    acc = fmaxf(acc, __shfl_xor(acc, 1, 64));
    acc = fmaxf(acc, __shfl_xor(acc, 2, 64));
    if (sub == 0) out[p] = fmaxf(acc, 0.f);   // layout == x_conv flatten [c][y][x]
}

// split-K: base[row] += partial dot(w1[row, seg], xconv[seg]); base pre-init to b1
#define NSEG 16
#define SEGLEN (CONV_FLAT / NSEG)   // 2048 floats
__global__ void base_acc_k(const float* __restrict__ w1, const float* __restrict__ xconv,
                           float* __restrict__ base) {
    int row = blockIdx.x >> 4;
    int seg = blockIdx.x & 15;
    const float2* wr = (const float2*)(w1 + (size_t)row * 32786) + seg * (SEGLEN / 2);
    const float2* xc = (const float2*)(xconv) + seg * (SEGLEN / 2);
    float acc = 0.f;
#pragma unroll
    for (int i = 0; i < 4; i++) {
        float2 a = wr[threadIdx.x + i * 256];
        float2 v = xc[threadIdx.x + i * 256];
        acc += a.x * v.x + a.y * v.y;
    }
#pragma unroll
    for (int off = 32; off > 0; off >>= 1)
        acc += __shfl_down(acc, off, 64);
    __shared__ float red[4];
    int lane = threadIdx.x & 63, wid = threadIdx.x >> 6;
    if (lane == 0) red[wid] = acc;
    __syncthreads();
    if (threadIdx.x == 0)
        atomicAdd(&base[row], red[0] + red[1] + red[2] + red[3]);
}

// pack small weights + init base = b1 (re-done every call: graph-replay safe)
// w2q[(k>>2)*704 + t*4 + (k&3)] = w2[t*304 + k]   (k<304, t<176)
// w3q[(k>>2)*192 + t*4 + (k&3)] = w3[t*176 + k]   (k<176, t<48)
__global__ void prep_k(const float* __restrict__ w1, const float* __restrict__ w2,
                       const float* __restrict__ w3, const float* __restrict__ b1,
                       float* __restrict__ w1pcT, float* __restrict__ w2q,
                       float* __restrict__ w3q, float* __restrict__ base) {
    int idx = blockIdx.x * blockDim.x + threadIdx.x;
    if (idx < 304 * 176) {
        int k = idx / 176, t = idx - k * 176;
        w2q[(k >> 2) * 704 + t * 4 + (k & 3)] = w2[t * 304 + k];
    }
    if (idx < 176 * 48) {
        int k = idx / 48, t = idx - k * 48;
        w3q[(k >> 2) * 192 + t * 4 + (k & 3)] = w3[t * 176 + k];
    }
    if (idx < 18 * 304) {                        // w1pcT[k*304+t] = w1[t, 32768+k]
        int k = idx / 304, t = idx - k * 304;
        w1pcT[idx] = w1[(size_t)t * 32786 + 32768 + k];
    }
    if (idx < H1_) base[idx] = b1[idx];
}

// fused per-chunk MLP, 4 chunks per block, 1024 blocks
#define CPB 4
__global__ void chunk_k(const float* __restrict__ x, const float* __restrict__ base,
                        const float* __restrict__ w1pcT, const float* __restrict__ w2q,
                        const float* __restrict__ b2, const float* __restrict__ w3q,
                        const float* __restrict__ b3, float* __restrict__ out) {
    __shared__ float pc[CPB][18];
    __shared__ float h1[CPB][H1_];   // rows 1216B: 16B aligned
    __shared__ float h2[CPB][H2_];
    int tid = threadIdx.x;
    int c0 = blockIdx.x * CPB;

    if (tid < CPB * 18) {
        int u = tid / 18, k = tid - u * 18;
        int c = c0 + u;
        int i = c >> 6, j = c & 63;
        float v;
        if (k == 0)      v = (float)(i * 4);
        else if (k == 1) v = (float)(j * 4);
        else {
            int kk = k - 2;
            int r = kk >> 2, cc = kk & 3;
            v = x[(i * 4 + r) * 256 + j * 4 + cc];
        }
        pc[u][k] = v;
    }
    __syncthreads();

    // h1: 304 outputs x CPB chunks
    for (int t = tid; t < H1_; t += 256) {
        float bb = base[t];
        float acc[CPB];
#pragma unroll
        for (int u = 0; u < CPB; u++) acc[u] = bb;
#pragma unroll
        for (int k = 0; k < 18; k++) {
            float w = w1pcT[k * H1_ + t];
#pragma unroll
            for (int u = 0; u < CPB; u++) acc[u] += w * pc[u][k];
        }
#pragma unroll
        for (int u = 0; u < CPB; u++) h1[u][t] = fmaxf(acc[u], 0.f);
    }
    __syncthreads();

    // h2: 176 outputs x CPB chunks; w2q float4 coalesced, h1 float4 broadcast
    if (tid < H2_) {
        const float4* wq = (const float4*)w2q;   // [76][176] float4s
        float acc[CPB];
#pragma unroll
        for (int u = 0; u < CPB; u++) acc[u] = b2[tid];
#pragma unroll 4
        for (int g = 0; g < 76; g++) {
            float4 w = wq[g * H2_ + tid];
#pragma unroll
            for (int u = 0; u < CPB; u++) {
                float4 h = *(const float4*)&h1[u][g * 4];
                acc[u] += w.x * h.x + w.y * h.y + w.z * h.z + w.w * h.w;
            }
        }
#pragma unroll
        for (int u = 0; u < CPB; u++) h2[u][tid] = fmaxf(acc[u], 0.f);
    }
    __syncthreads();

    // out: 48 outputs x CPB chunks = 192 threads; w3q float4 coalesced
    if (tid < CPB * OUT_) {
        int u = tid / OUT_, t = tid - u * OUT_;
        const float4* wq = (const float4*)w3q;   // [44][48] float4s
        float acc = b3[t];
#pragma unroll 4
        for (int g = 0; g < 44; g++) {
            float4 w = wq[g * OUT_ + t];
            float4 h = *(const float4*)&h2[u][g * 4];
            acc += w.x * h.x + w.y * h.y + w.z * h.z + w.w * h.w;
        }
        out[(size_t)(c0 + u) * OUT_ + t] = 1.f / (1.f + expf(-acc));
    }
}

extern "C" void kernel_launch(void* const* d_in, const int* in_sizes, int n_in,
                              void* d_out, int out_size, void* d_ws, size_t ws_size,
                              hipStream_t stream) {
    const float* x    = (const float*)d_in[0];
    const float* c1_w = (const float*)d_in[1];
    const float* c1_b = (const float*)d_in[2];
    const float* c2_w = (const float*)d_in[3];
    const float* c2_b = (const float*)d_in[4];
    const float* c3_w = (const float*)d_in[5];
    const float* c3_b = (const float*)d_in[6];
    const float* w1   = (const float*)d_in[7];
    const float* b1   = (const float*)d_in[8];
    const float* w2   = (const float*)d_in[9];
    const float* b2   = (const float*)d_in[10];
    const float* w3   = (const float*)d_in[11];
    const float* b3   = (const float*)d_in[12];
    float* out = (float*)d_out;
    float* ws  = (float*)d_ws;

    float* c1o    = ws + WS_C1;
    float* c2o    = ws + WS_C2;
    float* xconv  = ws + WS_XC;
    float* base   = ws + WS_BASE;
    float* w1pcT  = ws + WS_W1PCT;
    float* w2q    = ws + WS_W2Q;
    float* w3q    = ws + WS_W3Q;

    prep_k<<<(304 * 176 + 255) / 256, 256, 0, stream>>>(w1, w2, w3, b1, w1pcT, w2q, w3q, base);
    conv1_k<<<2048, 256, 0, stream>>>(x, c1_w, c1_b, c1o);
    conv2_k<<<1024, 256, 0, stream>>>(c1o, c2_w, c2_b, c2o);
    conv3_k<<<512, 256, 0, stream>>>(c2o, c3_w, c3_b, xconv);
    base_acc_k<<<H1_ * NSEG, 256, 0, stream>>>(w1, xconv, base);
    chunk_k<<<1024, 256, 0, stream>>>(x, base, w1pcT, w2q, b2, w3q, b3, out);
}